// Round 1
// 4144.644 us; speedup vs baseline: 1.9233x; 1.9233x over previous
//
#include <hip/hip_runtime.h>
#include <math.h>

typedef unsigned short u16;
typedef __attribute__((ext_vector_type(8))) short short8;
typedef __attribute__((ext_vector_type(4))) float f32x4;

namespace {
constexpr int D = 1024;
constexpr int B = 16;
constexpr int T = 2048;
constexpr int L = 16;
constexpr int C = T / L;          // 128 chunks
constexpr float SR  = 0.999f;
constexpr float EPS = 1e-8f;
constexpr int SLICE = L * B * D;  // 262144 floats: one out slice == one chunk's h rows
}

__device__ __forceinline__ u16 f2b(float f) {
  unsigned u = __float_as_uint(f);
  unsigned r = (u + 0x7fffu + ((u >> 16) & 1u)) >> 16;
  return (u16)r;
}
__device__ __forceinline__ float b2f(u16 v) {
  return __uint_as_float(((unsigned)v) << 16);
}

// ---------------- spectral norm (f32, small) ----------------

__global__ void mvT_kernel(const float* __restrict__ W, const float* __restrict__ vin,
                           float* __restrict__ vout) {
  int j = blockIdx.x * 256 + threadIdx.x;
  float acc = 0.f;
#pragma unroll 4
  for (int i = 0; i < D; ++i) acc += vin[i] * W[i * D + j];
  vout[j] = acc;
}

__global__ void mvN_kernel(const float* __restrict__ W, const float* __restrict__ vin,
                           float* __restrict__ vout) {
  __shared__ float red[256];
  int i = blockIdx.x, tid = threadIdx.x;
  float acc = 0.f;
  for (int j = tid; j < D; j += 256) acc += W[i * D + j] * vin[j];
  red[tid] = acc; __syncthreads();
  for (int s = 128; s > 0; s >>= 1) {
    if (tid < s) red[tid] += red[tid + s];
    __syncthreads();
  }
  if (tid == 0) vout[i] = red[0];
}

__global__ void scale_kernel(const float* __restrict__ t5, const float* __restrict__ t6,
                             float* __restrict__ scale_out) {
  __shared__ float r5[256], r6[256];
  int tid = threadIdx.x;
  float a5 = 0.f, a6 = 0.f;
  for (int i = tid; i < D; i += 256) { float x5 = t5[i], x6 = t6[i]; a5 += x5 * x5; a6 += x6 * x6; }
  r5[tid] = a5; r6[tid] = a6; __syncthreads();
  for (int s = 128; s > 0; s >>= 1) {
    if (tid < s) { r5[tid] += r5[tid + s]; r6[tid] += r6[tid + s]; }
    __syncthreads();
  }
  if (tid == 0) {
    float n5 = sqrtf(r5[0]), n6 = sqrtf(r6[0]);
    float sigma = n6 / (n5 + EPS);
    scale_out[0] = SR / (sigma + EPS);
  }
}

// Wn_bf16[e][d] = bf16(s*W[e][d]);  WnT_bf16[d][e] = bf16(s*W[e][d])
__global__ void cast_kernel(const float* __restrict__ W, const float* __restrict__ sc,
                            u16* __restrict__ WnB, u16* __restrict__ WnBT) {
  __shared__ float tile[32][33];
  float s = sc[0];
  int tx = threadIdx.x, ty = threadIdx.y;
  int bx = blockIdx.x, by = blockIdx.y;
#pragma unroll
  for (int k = 0; k < 4; ++k) {
    float v = W[(by * 32 + ty + 8 * k) * D + bx * 32 + tx];
    tile[ty + 8 * k][tx] = v;
    WnB[(by * 32 + ty + 8 * k) * D + bx * 32 + tx] = f2b(s * v);
  }
  __syncthreads();
#pragma unroll
  for (int k = 0; k < 4; ++k)
    WnBT[(bx * 32 + ty + 8 * k) * D + by * 32 + tx] = f2b(s * tile[tx][ty + 8 * k]);
}

// (O, OT) = (S*S, (S*S)^T), all bf16, via MFMA. Needs S row-major and ST row-major.
__global__ __launch_bounds__(256)
void sqb_kernel(const u16* __restrict__ S, const u16* __restrict__ ST,
                u16* __restrict__ O, u16* __restrict__ OT) {
  const int tid = threadIdx.x;
  const int lane = tid & 63, wave = tid >> 6;
  const int lrow = lane & 15, quad = lane >> 4;
  const int m0 = blockIdx.y * 64;
  const int n0 = blockIdx.x * 64 + wave * 16;
  const short8* S8  = (const short8*)S;
  const short8* ST8 = (const short8*)ST;
  f32x4 acc[4];
#pragma unroll
  for (int i = 0; i < 4; ++i) acc[i] = (f32x4){0.f, 0.f, 0.f, 0.f};
  for (int kk = 0; kk < 32; ++kk) {
    short8 bfrag = ST8[(size_t)(n0 + lrow) * 128 + kk * 4 + quad];
#pragma unroll
    for (int mt = 0; mt < 4; ++mt) {
      short8 afrag = S8[(size_t)(m0 + mt * 16 + lrow) * 128 + kk * 4 + quad];
      acc[mt] = __builtin_amdgcn_mfma_f32_16x16x32_bf16(afrag, bfrag, acc[mt], 0, 0, 0);
    }
  }
#pragma unroll
  for (int mt = 0; mt < 4; ++mt)
#pragma unroll
    for (int r = 0; r < 4; ++r) {
      int m = m0 + mt * 16 + quad * 4 + r;
      int n = n0 + lrow;
      u16 v = f2b(acc[mt][r]);
      O[(size_t)m * D + n] = v;
      OT[(size_t)n * D + m] = v;
    }
}

// h row 0 = h0; stash s_0 = h0 at out slice 0; zero barrier counters
__global__ void init_kernel(const float* __restrict__ h0, float* __restrict__ hbuf,
                            float* __restrict__ out, int* cnt, int* gen) {
  int i = blockIdx.x * 256 + threadIdx.x;
  float4 v = ((const float4*)h0)[i];
  ((float4*)hbuf)[i] = v;
  ((float4*)out)[i]  = v;
  if (i == 0) { *cnt = 0; *gen = 0; }
}

// ---------------- phase 1: per-chunk local recurrence (bf16 MFMA) ----------------
// One block per chunk. G (16 x 1024, bf16) in LDS = MFMA A operand (m=lane&15,
// k=quad*8+j contiguous => row-major). B operand from global Wn row-major
// (B[k][n] = Wn[n][k], lane reads 8 contiguous k from row n).
__global__ __launch_bounds__(256)
void phase1_kernel(const float* __restrict__ x, const u16* __restrict__ WnB,
                   const float* __restrict__ bias, float* __restrict__ hbuf) {
  __shared__ u16 G[16 * 1024];
  const int tid = threadIdx.x;
  const int c = blockIdx.x;
  const int lane = tid & 63, wave = tid >> 6;
  const int lrow = lane & 15, quad = lane >> 4;
  const int nbase = wave * 256;
  const short8* Wn8 = (const short8*)WnB;
  const short8* G8 = (const short8*)G;

  {
    const float4* X4 = (const float4*)(x + (size_t)c * SLICE);
    ushort4* G4 = (ushort4*)G;
    for (int i = tid; i < 4096; i += 256) {
      float4 v = X4[i];
      ushort4 g; g.x = f2b(v.x); g.y = f2b(v.y); g.z = f2b(v.z); g.w = f2b(v.w);
      G4[i] = g;
    }
  }

  float bcol[16];
#pragma unroll
  for (int tl = 0; tl < 16; ++tl) bcol[tl] = bias[nbase + tl * 16 + lrow];

  __syncthreads();

  for (int j = 1; j <= L; ++j) {
    f32x4 acc[16];
#pragma unroll
    for (int tl = 0; tl < 16; ++tl)
      acc[tl] = (f32x4){bcol[tl], bcol[tl], bcol[tl], bcol[tl]};

#pragma unroll
    for (int tp = 0; tp < 8; ++tp) {
      const short8* B0 = Wn8 + (size_t)(nbase + tp * 32 + lrow) * 128;
      const short8* B1 = B0 + 16 * 128;
      f32x4 a0 = acc[2 * tp], a1 = acc[2 * tp + 1];
#pragma unroll 8
      for (int kk = 0; kk < 32; ++kk) {
        short8 av = G8[lrow * 128 + kk * 4 + quad];
        a0 = __builtin_amdgcn_mfma_f32_16x16x32_bf16(av, B0[kk * 4 + quad], a0, 0, 0, 0);
        a1 = __builtin_amdgcn_mfma_f32_16x16x32_bf16(av, B1[kk * 4 + quad], a1, 0, 0, 0);
      }
      acc[2 * tp] = a0; acc[2 * tp + 1] = a1;
    }

    __syncthreads();   // all waves done reading G before overwrite

    const int t = c * L + j;
    float* hrow = hbuf + (size_t)t * (B * D);
    const float* xrow = x + (size_t)t * (B * D);  // only dereferenced when j < L
#pragma unroll
    for (int tl = 0; tl < 16; ++tl) {
      const int n = nbase + tl * 16 + lrow;
#pragma unroll
      for (int r = 0; r < 4; ++r) {
        const int b = quad * 4 + r;
        float hv = acc[tl][r];
        hrow[b * 1024 + n] = hv;
        if (j < L) G[b * 1024 + n] = f2b(hv + xrow[b * 1024 + n]);
      }
    }
    __syncthreads();
  }
}

// ---------------- phase 2: boundary chain, one kernel, grid barrier ----------------

__device__ __forceinline__ void grid_bar(int* cnt, int* gen, int nblk) {
  __syncthreads();
  if (threadIdx.x == 0) {
    __threadfence();
    int g = __hip_atomic_load(gen, __ATOMIC_RELAXED, __HIP_MEMORY_SCOPE_AGENT);
    int prev = __hip_atomic_fetch_add(cnt, 1, __ATOMIC_ACQ_REL, __HIP_MEMORY_SCOPE_AGENT);
    if (prev == nblk - 1) {
      __hip_atomic_store(cnt, 0, __ATOMIC_RELAXED, __HIP_MEMORY_SCOPE_AGENT);
      __hip_atomic_fetch_add(gen, 1, __ATOMIC_RELEASE, __HIP_MEMORY_SCOPE_AGENT);
    } else {
      while (__hip_atomic_load(gen, __ATOMIC_ACQUIRE, __HIP_MEMORY_SCOPE_AGENT) == g)
        __builtin_amdgcn_s_sleep(1);
    }
  }
  __syncthreads();
}

// Convert f32 state slice [16][1024] -> LDS bf16 hi/lo, XOR-swizzled.
// Swizzle: byte_off ^= (row&7)<<4  (row = batch index). ushort4 units: i ^ ((row&7)<<1).
__device__ __forceinline__ void load_state(const float* __restrict__ src,
                                           u16* Ghi, u16* Glo, int tid) {
  const float4* S4 = (const float4*)src;
  ushort4* H4 = (ushort4*)Ghi;
  ushort4* L4 = (ushort4*)Glo;
  for (int i = tid; i < 4096; i += 256) {
    float4 v = S4[i];
    ushort4 h, l;
    h.x = f2b(v.x); h.y = f2b(v.y); h.z = f2b(v.z); h.w = f2b(v.w);
    l.x = f2b(v.x - b2f(h.x)); l.y = f2b(v.y - b2f(h.y));
    l.z = f2b(v.z - b2f(h.z)); l.w = f2b(v.w - b2f(h.w));
    int si = i ^ (((i >> 8) & 7) << 1);
    H4[si] = h; L4[si] = l;
  }
}

// s_{c+1} = A16 * s_c + hl[(c+1)*L];  s_c stashed at out slice c start.
// Persistent cooperative MFMA kernel: 16 blocks x 4 waves; wave owns a 16-col
// tile of the 16x1024 state and keeps its A16 B-fragments (32x short8, 128
// VGPRs) in registers across all 127 steps. State is staged in LDS as bf16
// hi+lo (split precision ~ f32) per step.
__global__ __launch_bounds__(256)
void phase2_kernel(const u16* __restrict__ A16, const float* __restrict__ hbuf,
                   float* __restrict__ out, int* cnt, int* gen) {
  __shared__ u16 Ghi[16 * 1024];
  __shared__ u16 Glo[16 * 1024];
  const int tid = threadIdx.x;
  const int lane = tid & 63, wave = tid >> 6;
  const int lrow = lane & 15, quad = lane >> 4;
  const int e = (blockIdx.x * 4 + wave) * 16 + lrow;   // output column (n)
  const int nblk = gridDim.x;
  const short8* A8   = (const short8*)A16;
  const short8* Ghi8 = (const short8*)Ghi;
  const short8* Glo8 = (const short8*)Glo;

  // B fragments: B[k][n] = A16[n][k]; lane reads row n=e, 8 contiguous k per quad.
  short8 bfrag[32];
#pragma unroll
  for (int kk = 0; kk < 32; ++kk)
    bfrag[kk] = A8[(size_t)e * 128 + kk * 4 + quad];

  // s_0 lives at out slice 0 (stashed by init_kernel)
  load_state(out, Ghi, Glo, tid);

  // prefetch hl for step c=0 (h-local at t=(c+1)*L, slice 1 of hbuf)
  float hl[4];
#pragma unroll
  for (int r = 0; r < 4; ++r) hl[r] = hbuf[(size_t)1 * SLICE + (quad * 4 + r) * 1024 + e];

  const int base = lrow * 128 + quad;
  const int swz = lrow & 7;
  for (int c = 0; c < C - 1; ++c) {
    __syncthreads();   // LDS state ready
    // 4 independent MFMA chains (1 wave/SIMD here -> need ILP, not TLP)
    f32x4 a0 = (f32x4){0.f, 0.f, 0.f, 0.f};
    f32x4 a1 = (f32x4){0.f, 0.f, 0.f, 0.f};
    f32x4 a2 = (f32x4){0.f, 0.f, 0.f, 0.f};
    f32x4 a3 = (f32x4){0.f, 0.f, 0.f, 0.f};
#pragma unroll
    for (int kk = 0; kk < 32; kk += 2) {
      int s0 = (base + kk * 4) ^ swz;
      int s1 = (base + kk * 4 + 4) ^ swz;
      a0 = __builtin_amdgcn_mfma_f32_16x16x32_bf16(Ghi8[s0], bfrag[kk],     a0, 0, 0, 0);
      a1 = __builtin_amdgcn_mfma_f32_16x16x32_bf16(Glo8[s0], bfrag[kk],     a1, 0, 0, 0);
      a2 = __builtin_amdgcn_mfma_f32_16x16x32_bf16(Ghi8[s1], bfrag[kk + 1], a2, 0, 0, 0);
      a3 = __builtin_amdgcn_mfma_f32_16x16x32_bf16(Glo8[s1], bfrag[kk + 1], a3, 0, 0, 0);
    }
    f32x4 acc = (a0 + a1) + (a2 + a3);

    // epilogue: s_{c+1}[b][e] = acc + hl ; D-layout: col=lane&15 (=e), row b=quad*4+r
    float* orow = out + (size_t)(c + 1) * SLICE + e;
#pragma unroll
    for (int r = 0; r < 4; ++r) orow[(quad * 4 + r) * 1024] = acc[r] + hl[r];

    if (c < C - 2) {
      // prefetch next step's hl; loads drain during the barrier spin
      const float* hlp = hbuf + (size_t)(c + 2) * SLICE + e;
#pragma unroll
      for (int r = 0; r < 4; ++r) hl[r] = hlp[(quad * 4 + r) * 1024];
      grid_bar(cnt, gen, nblk);
      load_state(out + (size_t)(c + 1) * SLICE, Ghi, Glo, tid);
    }
  }
}

// ---------------- phase 3: w_j = A^j s_c; h = hl + w; out = h^2*sigmoid(h) ----------------

__global__ __launch_bounds__(256)
void phase3_kernel(const u16* __restrict__ WnB, float* __restrict__ hbuf,
                   float* __restrict__ out) {
  __shared__ u16 G[16 * 1024];
  const int tid = threadIdx.x;
  const int c = blockIdx.x;
  const int lane = tid & 63, wave = tid >> 6;
  const int lrow = lane & 15, quad = lane >> 4;
  const int nbase = wave * 256;
  const short8* Wn8 = (const short8*)WnB;
  const short8* G8 = (const short8*)G;

  {
    const float4* S4 = (const float4*)(out + (size_t)c * SLICE);
    ushort4* G4 = (ushort4*)G;
    for (int i = tid; i < 4096; i += 256) {
      float4 v = S4[i];
      ushort4 g; g.x = f2b(v.x); g.y = f2b(v.y); g.z = f2b(v.z); g.w = f2b(v.w);
      G4[i] = g;
    }
  }
  __syncthreads();

  for (int j = 1; j <= L; ++j) {
    f32x4 acc[16];
#pragma unroll
    for (int tl = 0; tl < 16; ++tl) acc[tl] = (f32x4){0.f, 0.f, 0.f, 0.f};

#pragma unroll
    for (int tp = 0; tp < 8; ++tp) {
      const short8* B0 = Wn8 + (size_t)(nbase + tp * 32 + lrow) * 128;
      const short8* B1 = B0 + 16 * 128;
      f32x4 a0 = acc[2 * tp], a1 = acc[2 * tp + 1];
#pragma unroll 8
      for (int kk = 0; kk < 32; ++kk) {
        short8 av = G8[lrow * 128 + kk * 4 + quad];
        a0 = __builtin_amdgcn_mfma_f32_16x16x32_bf16(av, B0[kk * 4 + quad], a0, 0, 0, 0);
        a1 = __builtin_amdgcn_mfma_f32_16x16x32_bf16(av, B1[kk * 4 + quad], a1, 0, 0, 0);
      }
      acc[2 * tp] = a0; acc[2 * tp + 1] = a1;
    }

    __syncthreads();

    const int t = c * L + j;
    float* hrow = hbuf + (size_t)t * (B * D);
    float* orow = out + (size_t)(t - 1) * (B * D);
#pragma unroll
    for (int tl = 0; tl < 16; ++tl) {
      const int n = nbase + tl * 16 + lrow;
#pragma unroll
      for (int r = 0; r < 4; ++r) {
        const int b = quad * 4 + r;
        float wv = acc[tl][r];
        float hv = hrow[b * 1024 + n] + wv;
        hrow[b * 1024 + n] = hv;
        float o = hv * hv / (1.f + __expf(-hv));
        orow[b * 1024 + n] = o;
        if (j < L) G[b * 1024 + n] = f2b(wv);
      }
    }
    __syncthreads();
  }
}

// ---------------- launch ----------------

extern "C" void kernel_launch(void* const* d_in, const int* in_sizes, int n_in,
                              void* d_out, int out_size, void* d_ws, size_t ws_size,
                              hipStream_t stream) {
  const float* x    = (const float*)d_in[0];
  const float* h0   = (const float*)d_in[1];
  const float* W    = (const float*)d_in[2];
  const float* bias = (const float*)d_in[3];
  const float* u    = (const float*)d_in[4];
  float* out  = (float*)d_out;
  float* hbuf = out + (size_t)T * B * D;

  char* wsb = (char*)d_ws;
  float* va = (float*)wsb;
  float* vb = (float*)(wsb + 4096);
  float* sc = (float*)(wsb + 8192);
  int* cnt  = (int*)(wsb + 8192 + 64);
  int* gen  = cnt + 1;
  u16* WnB  = (u16*)(wsb + 16384);
  u16* WnBT = WnB  + (size_t)D * D;
  u16* P1   = WnBT + (size_t)D * D;
  u16* P1T  = P1   + (size_t)D * D;
  u16* P2   = P1T  + (size_t)D * D;
  u16* P2T  = P2   + (size_t)D * D;

  // spectral norm: 6 matvecs; sigma = ||W v3|| / ||v3||
  mvT_kernel<<<4, 256, 0, stream>>>(W, u, va);
  mvN_kernel<<<1024, 256, 0, stream>>>(W, va, vb);
  mvT_kernel<<<4, 256, 0, stream>>>(W, vb, va);
  mvN_kernel<<<1024, 256, 0, stream>>>(W, va, vb);
  mvT_kernel<<<4, 256, 0, stream>>>(W, vb, va);
  mvN_kernel<<<1024, 256, 0, stream>>>(W, va, vb);
  scale_kernel<<<1, 256, 0, stream>>>(va, vb, sc);

  cast_kernel<<<dim3(32, 32), dim3(32, 8), 0, stream>>>(W, sc, WnB, WnBT);

  // (A^16) via 4 bf16 MFMA squarings (keep both orientations each level)
  sqb_kernel<<<dim3(16, 16), 256, 0, stream>>>(WnB, WnBT, P1, P1T);  // A^2
  sqb_kernel<<<dim3(16, 16), 256, 0, stream>>>(P1, P1T, P2, P2T);    // A^4
  sqb_kernel<<<dim3(16, 16), 256, 0, stream>>>(P2, P2T, P1, P1T);    // A^8
  sqb_kernel<<<dim3(16, 16), 256, 0, stream>>>(P1, P1T, P2, P2T);    // A^16

  init_kernel<<<16, 256, 0, stream>>>(h0, hbuf, out, cnt, gen);

  phase1_kernel<<<C, 256, 0, stream>>>(x, WnB, bias, hbuf);

  // row-major A^16 (P2): B-operand source for MFMA (B[k][n] = A16[n][k])
  phase2_kernel<<<16, 256, 0, stream>>>(P2, hbuf, out, cnt, gen);

  phase3_kernel<<<C, 256, 0, stream>>>(WnB, hbuf, out);
}

// Round 2
// 2977.679 us; speedup vs baseline: 2.6771x; 1.3919x over previous
//
#include <hip/hip_runtime.h>
#include <math.h>

typedef unsigned short u16;
typedef __attribute__((ext_vector_type(8))) short short8;
typedef __attribute__((ext_vector_type(4))) float f32x4;

namespace {
constexpr int D = 1024;
constexpr int B = 16;
constexpr int T = 2048;
constexpr int L = 16;
constexpr int C = T / L;          // 128 chunks
constexpr float SR  = 0.999f;
constexpr float EPS = 1e-8f;
constexpr int SLICE = L * B * D;  // 262144 floats
constexpr int BD = B * D;         // 16384
}

__device__ __forceinline__ u16 f2b(float f) {
  unsigned u = __float_as_uint(f);
  unsigned r = (u + 0x7fffu + ((u >> 16) & 1u)) >> 16;
  return (u16)r;
}
__device__ __forceinline__ float b2f(u16 v) {
  return __uint_as_float(((unsigned)v) << 16);
}

__device__ __forceinline__ short8 pack8(float4 a, float4 b) {
  short8 s;
  s[0] = (short)f2b(a.x); s[1] = (short)f2b(a.y);
  s[2] = (short)f2b(a.z); s[3] = (short)f2b(a.w);
  s[4] = (short)f2b(b.x); s[5] = (short)f2b(b.y);
  s[6] = (short)f2b(b.z); s[7] = (short)f2b(b.w);
  return s;
}

// ---------------- spectral norm (f32, small) ----------------

__global__ void mvT_kernel(const float* __restrict__ W, const float* __restrict__ vin,
                           float* __restrict__ vout) {
  int j = blockIdx.x * 256 + threadIdx.x;
  float acc = 0.f;
#pragma unroll 4
  for (int i = 0; i < D; ++i) acc += vin[i] * W[i * D + j];
  vout[j] = acc;
}

__global__ void mvN_kernel(const float* __restrict__ W, const float* __restrict__ vin,
                           float* __restrict__ vout) {
  __shared__ float red[256];
  int i = blockIdx.x, tid = threadIdx.x;
  float acc = 0.f;
  for (int j = tid; j < D; j += 256) acc += W[i * D + j] * vin[j];
  red[tid] = acc; __syncthreads();
  for (int s = 128; s > 0; s >>= 1) {
    if (tid < s) red[tid] += red[tid + s];
    __syncthreads();
  }
  if (tid == 0) vout[i] = red[0];
}

__global__ void scale_kernel(const float* __restrict__ t5, const float* __restrict__ t6,
                             float* __restrict__ scale_out) {
  __shared__ float r5[256], r6[256];
  int tid = threadIdx.x;
  float a5 = 0.f, a6 = 0.f;
  for (int i = tid; i < D; i += 256) { float x5 = t5[i], x6 = t6[i]; a5 += x5 * x5; a6 += x6 * x6; }
  r5[tid] = a5; r6[tid] = a6; __syncthreads();
  for (int s = 128; s > 0; s >>= 1) {
    if (tid < s) { r5[tid] += r5[tid + s]; r6[tid] += r6[tid + s]; }
    __syncthreads();
  }
  if (tid == 0) {
    float n5 = sqrtf(r5[0]), n6 = sqrtf(r6[0]);
    float sigma = n6 / (n5 + EPS);
    scale_out[0] = SR / (sigma + EPS);
  }
}

__global__ void cast_kernel(const float* __restrict__ W, const float* __restrict__ sc,
                            u16* __restrict__ WnB, u16* __restrict__ WnBT) {
  __shared__ float tile[32][33];
  float s = sc[0];
  int tx = threadIdx.x, ty = threadIdx.y;
  int bx = blockIdx.x, by = blockIdx.y;
#pragma unroll
  for (int k = 0; k < 4; ++k) {
    float v = W[(by * 32 + ty + 8 * k) * D + bx * 32 + tx];
    tile[ty + 8 * k][tx] = v;
    WnB[(by * 32 + ty + 8 * k) * D + bx * 32 + tx] = f2b(s * v);
  }
  __syncthreads();
#pragma unroll
  for (int k = 0; k < 4; ++k)
    WnBT[(bx * 32 + ty + 8 * k) * D + by * 32 + tx] = f2b(s * tile[tx][ty + 8 * k]);
}

__global__ __launch_bounds__(256)
void sqb_kernel(const u16* __restrict__ S, const u16* __restrict__ ST,
                u16* __restrict__ O, u16* __restrict__ OT) {
  const int tid = threadIdx.x;
  const int lane = tid & 63, wave = tid >> 6;
  const int lrow = lane & 15, quad = lane >> 4;
  const int m0 = blockIdx.y * 64;
  const int n0 = blockIdx.x * 64 + wave * 16;
  const short8* S8  = (const short8*)S;
  const short8* ST8 = (const short8*)ST;
  f32x4 acc[4];
#pragma unroll
  for (int i = 0; i < 4; ++i) acc[i] = (f32x4){0.f, 0.f, 0.f, 0.f};
  for (int kk = 0; kk < 32; ++kk) {
    short8 bfrag = ST8[(size_t)(n0 + lrow) * 128 + kk * 4 + quad];
#pragma unroll
    for (int mt = 0; mt < 4; ++mt) {
      short8 afrag = S8[(size_t)(m0 + mt * 16 + lrow) * 128 + kk * 4 + quad];
      acc[mt] = __builtin_amdgcn_mfma_f32_16x16x32_bf16(afrag, bfrag, acc[mt], 0, 0, 0);
    }
  }
#pragma unroll
  for (int mt = 0; mt < 4; ++mt)
#pragma unroll
    for (int r = 0; r < 4; ++r) {
      int m = m0 + mt * 16 + quad * 4 + r;
      int n = n0 + lrow;
      u16 v = f2b(acc[mt][r]);
      O[(size_t)m * D + n] = v;
      OT[(size_t)n * D + m] = v;
    }
}

// h row 0 = h0; stash s_0 = h0 at out slice 0; zero 32 group-barrier slots
__global__ void init_kernel(const float* __restrict__ h0, float* __restrict__ hbuf,
                            float* __restrict__ out, int* cnts, int* gens) {
  int i = blockIdx.x * 256 + threadIdx.x;
  float4 v = ((const float4*)h0)[i];
  ((float4*)hbuf)[i] = v;
  ((float4*)out)[i]  = v;
  if (i < 32) { cnts[i] = 0; gens[i] = 0; }
}

// ---------------- group barrier ----------------

__device__ __forceinline__ void grid_bar(int* cnt, int* gen, int nblk) {
  __syncthreads();
  if (threadIdx.x == 0) {
    __threadfence();
    int g = __hip_atomic_load(gen, __ATOMIC_RELAXED, __HIP_MEMORY_SCOPE_AGENT);
    int prev = __hip_atomic_fetch_add(cnt, 1, __ATOMIC_ACQ_REL, __HIP_MEMORY_SCOPE_AGENT);
    if (prev == nblk - 1) {
      __hip_atomic_store(cnt, 0, __ATOMIC_RELAXED, __HIP_MEMORY_SCOPE_AGENT);
      __hip_atomic_fetch_add(gen, 1, __ATOMIC_RELEASE, __HIP_MEMORY_SCOPE_AGENT);
    } else {
      while (__hip_atomic_load(gen, __ATOMIC_ACQUIRE, __HIP_MEMORY_SCOPE_AGENT) == g)
        __builtin_amdgcn_s_sleep(1);
    }
  }
  __syncthreads();
}

// ---------------- phase 1: grid-wide stepped GEMM ----------------
// M=2048 rows (=(chunk c, batch b)), N=1024, K=1024, 16 steps.
// 256 blocks x 512 thr (8 waves). Block (mb,nb): rows [mb*64,+64), cols [nb*128,+128).
// Wave holds its 16 cols' Wn B-fragments in regs for the whole kernel (128 VGPR).
// A-state bf16(h+x) staged per K-chunk (64x128) into double-buffered LDS with
// XOR swizzle: LDS slot (row, v) holds data unit v^(row&7) (16B units) -> 2-way
// bank floor on both ds_write and ds_read.
// Step j reads hbuf rows t=c*L+j-1, writes rows t=c*L+j -> no intra-step race;
// 32 independent 8-block groups (4 chunks each), per-group barrier between steps.
// Block-index swizzle keeps each group on one XCD (perf only).
__global__ __launch_bounds__(512, 2)
void phase1_kernel(const float* __restrict__ x, const u16* __restrict__ WnB,
                   const float* __restrict__ bias, float* __restrict__ hbuf,
                   int* cnts, int* gens) {
  __shared__ u16 Abuf[2][64 * 128];
  const int tid = threadIdx.x;
  const int lane = tid & 63, wave = tid >> 6;
  const int lrow = lane & 15, quad = lane >> 4;
  const int bid = blockIdx.x;
  const int mb = ((bid >> 6) << 3) | (bid & 7);  // group id 0..31 (XCD-local group)
  const int nb = (bid >> 3) & 7;
  const int gr0 = mb * 64;
  const int nw = nb * 128 + wave * 16 + lrow;    // this lane's output column
  const short8* Wn8 = (const short8*)WnB;

  short8 bfrag[32];
#pragma unroll
  for (int kk = 0; kk < 32; ++kk)
    bfrag[kk] = Wn8[(size_t)nw * 128 + kk * 4 + quad];

  const float bcol = bias[nw];

  // staging mapping: thread covers slots (row0,v) and (row1,v)
  const int rr = tid >> 4;          // 0..31
  const int v_ = tid & 15;
  const int row0 = rr, row1 = 32 + rr;
  const int su0 = v_ ^ (row0 & 7), su1 = v_ ^ (row1 & 7);
  const int gra = gr0 + row0, grb = gr0 + row1;
  const int ca = gra >> 4, ba = gra & 15;
  const int cb = grb >> 4, bb = grb & 15;
  const size_t fa_base = (size_t)ba * 1024 + su0 * 8;  // f32 offset within row
  const size_t fb_base = (size_t)bb * 1024 + su1 * 8;
  const int slot0 = row0 * 16 + v_, slot1 = row1 * 16 + v_;

  auto stage_load = [&](int sc, int j, short8& s0, short8& s1) {
    const size_t ta = (size_t)(ca * L + j - 1) * BD + fa_base + sc * 128;
    const size_t tb = (size_t)(cb * L + j - 1) * BD + fb_base + sc * 128;
    float4 x0 = ((const float4*)(x + ta))[0];
    float4 x1 = ((const float4*)(x + ta))[1];
    float4 y0 = ((const float4*)(x + tb))[0];
    float4 y1 = ((const float4*)(x + tb))[1];
    if (j > 1) {
      float4 h0v = ((const float4*)(hbuf + ta))[0];
      float4 h1v = ((const float4*)(hbuf + ta))[1];
      float4 h2v = ((const float4*)(hbuf + tb))[0];
      float4 h3v = ((const float4*)(hbuf + tb))[1];
      x0.x += h0v.x; x0.y += h0v.y; x0.z += h0v.z; x0.w += h0v.w;
      x1.x += h1v.x; x1.y += h1v.y; x1.z += h1v.z; x1.w += h1v.w;
      y0.x += h2v.x; y0.y += h2v.y; y0.z += h2v.z; y0.w += h2v.w;
      y1.x += h3v.x; y1.y += h3v.y; y1.z += h3v.z; y1.w += h3v.w;
    }
    s0 = pack8(x0, x1);
    s1 = pack8(y0, y1);
  };

  for (int j = 1; j <= L; ++j) {
    short8 s0, s1;
    stage_load(0, j, s0, s1);
    ((short8*)Abuf[0])[slot0] = s0;
    ((short8*)Abuf[0])[slot1] = s1;

    f32x4 acc[4];
#pragma unroll
    for (int mt = 0; mt < 4; ++mt) acc[mt] = (f32x4){bcol, bcol, bcol, bcol};

#pragma unroll
    for (int cc = 0; cc < 8; ++cc) {
      const int cur = cc & 1;
      if (cc < 7) stage_load(cc + 1, j, s0, s1);
      __syncthreads();
      const short8* A8 = (const short8*)Abuf[cur];
#pragma unroll
      for (int kp = 0; kp < 4; ++kp) {
#pragma unroll
        for (int mt = 0; mt < 4; ++mt) {
          short8 av = A8[(mt * 16 + lrow) * 16 + ((kp * 4 + quad) ^ (lrow & 7))];
          acc[mt] = __builtin_amdgcn_mfma_f32_16x16x32_bf16(av, bfrag[cc * 4 + kp], acc[mt], 0, 0, 0);
        }
      }
      if (cc < 7) {
        short8* Wd = (short8*)Abuf[cur ^ 1];
        Wd[slot0] = s0;
        Wd[slot1] = s1;
      }
    }

#pragma unroll
    for (int mt = 0; mt < 4; ++mt) {
#pragma unroll
      for (int r = 0; r < 4; ++r) {
        const int gr = gr0 + mt * 16 + quad * 4 + r;
        const int c = gr >> 4, b = gr & 15;
        hbuf[(size_t)(c * L + j) * BD + (size_t)b * 1024 + nw] = acc[mt][r];
      }
    }
    if (j < L) grid_bar(&cnts[mb], &gens[mb], 8);
  }
}

// ---------------- phase 2: boundary chain (unchanged) ----------------

__device__ __forceinline__ void load_state(const float* __restrict__ src,
                                           u16* Ghi, u16* Glo, int tid) {
  const float4* S4 = (const float4*)src;
  ushort4* H4 = (ushort4*)Ghi;
  ushort4* L4 = (ushort4*)Glo;
  for (int i = tid; i < 4096; i += 256) {
    float4 v = S4[i];
    ushort4 h, l;
    h.x = f2b(v.x); h.y = f2b(v.y); h.z = f2b(v.z); h.w = f2b(v.w);
    l.x = f2b(v.x - b2f(h.x)); l.y = f2b(v.y - b2f(h.y));
    l.z = f2b(v.z - b2f(h.z)); l.w = f2b(v.w - b2f(h.w));
    int si = i ^ (((i >> 8) & 7) << 1);
    H4[si] = h; L4[si] = l;
  }
}

__global__ __launch_bounds__(256)
void phase2_kernel(const u16* __restrict__ A16, const float* __restrict__ hbuf,
                   float* __restrict__ out, int* cnt, int* gen) {
  __shared__ u16 Ghi[16 * 1024];
  __shared__ u16 Glo[16 * 1024];
  const int tid = threadIdx.x;
  const int lane = tid & 63, wave = tid >> 6;
  const int lrow = lane & 15, quad = lane >> 4;
  const int e = (blockIdx.x * 4 + wave) * 16 + lrow;
  const int nblk = gridDim.x;
  const short8* A8   = (const short8*)A16;
  const short8* Ghi8 = (const short8*)Ghi;
  const short8* Glo8 = (const short8*)Glo;

  short8 bfrag[32];
#pragma unroll
  for (int kk = 0; kk < 32; ++kk)
    bfrag[kk] = A8[(size_t)e * 128 + kk * 4 + quad];

  load_state(out, Ghi, Glo, tid);

  float hl[4];
#pragma unroll
  for (int r = 0; r < 4; ++r) hl[r] = hbuf[(size_t)1 * SLICE + (quad * 4 + r) * 1024 + e];

  const int base = lrow * 128 + quad;
  const int swz = lrow & 7;
  for (int c = 0; c < C - 1; ++c) {
    __syncthreads();
    f32x4 a0 = (f32x4){0.f, 0.f, 0.f, 0.f};
    f32x4 a1 = (f32x4){0.f, 0.f, 0.f, 0.f};
    f32x4 a2 = (f32x4){0.f, 0.f, 0.f, 0.f};
    f32x4 a3 = (f32x4){0.f, 0.f, 0.f, 0.f};
#pragma unroll
    for (int kk = 0; kk < 32; kk += 2) {
      int s0 = (base + kk * 4) ^ swz;
      int s1 = (base + kk * 4 + 4) ^ swz;
      a0 = __builtin_amdgcn_mfma_f32_16x16x32_bf16(Ghi8[s0], bfrag[kk],     a0, 0, 0, 0);
      a1 = __builtin_amdgcn_mfma_f32_16x16x32_bf16(Glo8[s0], bfrag[kk],     a1, 0, 0, 0);
      a2 = __builtin_amdgcn_mfma_f32_16x16x32_bf16(Ghi8[s1], bfrag[kk + 1], a2, 0, 0, 0);
      a3 = __builtin_amdgcn_mfma_f32_16x16x32_bf16(Glo8[s1], bfrag[kk + 1], a3, 0, 0, 0);
    }
    f32x4 acc = (a0 + a1) + (a2 + a3);

    float* orow = out + (size_t)(c + 1) * SLICE + e;
#pragma unroll
    for (int r = 0; r < 4; ++r) orow[(quad * 4 + r) * 1024] = acc[r] + hl[r];

    if (c < C - 2) {
      const float* hlp = hbuf + (size_t)(c + 2) * SLICE + e;
#pragma unroll
      for (int r = 0; r < 4; ++r) hl[r] = hlp[(quad * 4 + r) * 1024];
      grid_bar(cnt, gen, nblk);
      load_state(out + (size_t)(c + 1) * SLICE, Ghi, Glo, tid);
    }
  }
}

// Wping[gr][d] = bf16(s_c[b][d]) for gr=(c,b); s_c stashed at out slice c start.
__global__ void w0_kernel(const float* __restrict__ out, u16* __restrict__ Wping) {
  int i4 = blockIdx.x * 256 + threadIdx.x;   // 0..524287 ushort4 units
  int gr = i4 >> 8, du = i4 & 255;
  int c = gr >> 4, b = gr & 15;
  float4 v = ((const float4*)out)[(size_t)c * (SLICE / 4) + b * 256 + du];
  ushort4 g; g.x = f2b(v.x); g.y = f2b(v.y); g.z = f2b(v.z); g.w = f2b(v.w);
  ((ushort4*)Wping)[i4] = g;
}

// ---------------- phase 3: grid-wide stepped GEMM ----------------
// w_j = A * w_{j-1} (w_0 = s_c); h = hbuf + w; out = h^2*sigmoid(h).
// Same structure as phase1; w-state bf16 ping-pongs between two 4MB buffers
// (no intra-step read/write overlap -> single group barrier per step).
__global__ __launch_bounds__(512, 2)
void phase3_kernel(const u16* __restrict__ WnB, float* __restrict__ hbuf,
                   float* __restrict__ out, u16* __restrict__ Wping,
                   u16* __restrict__ Wpong, int* cnts, int* gens) {
  __shared__ u16 Abuf[2][64 * 128];
  const int tid = threadIdx.x;
  const int lane = tid & 63, wave = tid >> 6;
  const int lrow = lane & 15, quad = lane >> 4;
  const int bid = blockIdx.x;
  const int mb = ((bid >> 6) << 3) | (bid & 7);
  const int nb = (bid >> 3) & 7;
  const int gr0 = mb * 64;
  const int nw = nb * 128 + wave * 16 + lrow;
  const short8* Wn8 = (const short8*)WnB;

  short8 bfrag[32];
#pragma unroll
  for (int kk = 0; kk < 32; ++kk)
    bfrag[kk] = Wn8[(size_t)nw * 128 + kk * 4 + quad];

  const int rr = tid >> 4;
  const int v_ = tid & 15;
  const int row0 = rr, row1 = 32 + rr;
  const int su0 = v_ ^ (row0 & 7), su1 = v_ ^ (row1 & 7);
  const size_t gra = gr0 + row0, grb = gr0 + row1;
  const int slot0 = row0 * 16 + v_, slot1 = row1 * 16 + v_;

  for (int j = 1; j <= L; ++j) {
    const short8* Wsrc = (const short8*)((j & 1) ? Wping : Wpong);
    u16* Wdst = (j & 1) ? Wpong : Wping;

    short8 s0 = Wsrc[gra * 128 + 0 * 16 + su0];
    short8 s1 = Wsrc[grb * 128 + 0 * 16 + su1];
    ((short8*)Abuf[0])[slot0] = s0;
    ((short8*)Abuf[0])[slot1] = s1;

    f32x4 acc[4];
#pragma unroll
    for (int mt = 0; mt < 4; ++mt) acc[mt] = (f32x4){0.f, 0.f, 0.f, 0.f};

#pragma unroll
    for (int cc = 0; cc < 8; ++cc) {
      const int cur = cc & 1;
      if (cc < 7) {
        s0 = Wsrc[gra * 128 + (cc + 1) * 16 + su0];
        s1 = Wsrc[grb * 128 + (cc + 1) * 16 + su1];
      }
      __syncthreads();
      const short8* A8 = (const short8*)Abuf[cur];
#pragma unroll
      for (int kp = 0; kp < 4; ++kp) {
#pragma unroll
        for (int mt = 0; mt < 4; ++mt) {
          short8 av = A8[(mt * 16 + lrow) * 16 + ((kp * 4 + quad) ^ (lrow & 7))];
          acc[mt] = __builtin_amdgcn_mfma_f32_16x16x32_bf16(av, bfrag[cc * 4 + kp], acc[mt], 0, 0, 0);
        }
      }
      if (cc < 7) {
        short8* Wd = (short8*)Abuf[cur ^ 1];
        Wd[slot0] = s0;
        Wd[slot1] = s1;
      }
    }

#pragma unroll
    for (int mt = 0; mt < 4; ++mt) {
#pragma unroll
      for (int r = 0; r < 4; ++r) {
        const int gr = gr0 + mt * 16 + quad * 4 + r;
        const int c = gr >> 4, b = gr & 15;
        float wv = acc[mt][r];
        size_t off = (size_t)(c * L + j) * BD + (size_t)b * 1024 + nw;
        float hv = hbuf[off] + wv;
        hbuf[off] = hv;
        float o = hv * hv / (1.f + __expf(-hv));
        out[off - BD] = o;
        if (j < L) Wdst[(size_t)gr * 1024 + nw] = f2b(wv);
      }
    }
    if (j < L) grid_bar(&cnts[mb], &gens[mb], 8);
  }
}

// ---------------- launch ----------------

extern "C" void kernel_launch(void* const* d_in, const int* in_sizes, int n_in,
                              void* d_out, int out_size, void* d_ws, size_t ws_size,
                              hipStream_t stream) {
  const float* x    = (const float*)d_in[0];
  const float* h0   = (const float*)d_in[1];
  const float* W    = (const float*)d_in[2];
  const float* bias = (const float*)d_in[3];
  const float* u    = (const float*)d_in[4];
  float* out  = (float*)d_out;
  float* hbuf = out + (size_t)T * B * D;

  char* wsb = (char*)d_ws;
  float* va = (float*)wsb;
  float* vb = (float*)(wsb + 4096);
  float* sc = (float*)(wsb + 8192);
  int* cnts = (int*)(wsb + 8192 + 64);   // 32 group counters
  int* gens = cnts + 32;                 // 32 group generations
  u16* WnB  = (u16*)(wsb + 16384);
  u16* WnBT = WnB  + (size_t)D * D;
  u16* P1   = WnBT + (size_t)D * D;      // P1..P1T: 4MB, reused as w-ping after sqb
  u16* P1T  = P1   + (size_t)D * D;
  u16* P2   = P1T  + (size_t)D * D;      // P2..P2T: 4MB, A^16 then w-pong after phase2
  u16* P2T  = P2   + (size_t)D * D;

  // spectral norm: 6 matvecs; sigma = ||W v3|| / ||v3||
  mvT_kernel<<<4, 256, 0, stream>>>(W, u, va);
  mvN_kernel<<<1024, 256, 0, stream>>>(W, va, vb);
  mvT_kernel<<<4, 256, 0, stream>>>(W, vb, va);
  mvN_kernel<<<1024, 256, 0, stream>>>(W, va, vb);
  mvT_kernel<<<4, 256, 0, stream>>>(W, vb, va);
  mvN_kernel<<<1024, 256, 0, stream>>>(W, va, vb);
  scale_kernel<<<1, 256, 0, stream>>>(va, vb, sc);

  cast_kernel<<<dim3(32, 32), dim3(32, 8), 0, stream>>>(W, sc, WnB, WnBT);

  // A^16 via 4 bf16 MFMA squarings
  sqb_kernel<<<dim3(16, 16), 256, 0, stream>>>(WnB, WnBT, P1, P1T);  // A^2
  sqb_kernel<<<dim3(16, 16), 256, 0, stream>>>(P1, P1T, P2, P2T);    // A^4
  sqb_kernel<<<dim3(16, 16), 256, 0, stream>>>(P2, P2T, P1, P1T);    // A^8
  sqb_kernel<<<dim3(16, 16), 256, 0, stream>>>(P1, P1T, P2, P2T);    // A^16

  init_kernel<<<16, 256, 0, stream>>>(h0, hbuf, out, cnts, gens);

  phase1_kernel<<<256, 512, 0, stream>>>(x, WnB, bias, hbuf, cnts, gens);

  phase2_kernel<<<16, 256, 0, stream>>>(P2, hbuf, out, cnts, gens);

  w0_kernel<<<2048, 256, 0, stream>>>(out, P1);

  phase3_kernel<<<256, 512, 0, stream>>>(WnB, hbuf, out, P1, P2, cnts, gens);
}

// Round 3
// 1791.045 us; speedup vs baseline: 4.4508x; 1.6625x over previous
//
#include <hip/hip_runtime.h>
#include <math.h>

typedef unsigned short u16;
typedef __attribute__((ext_vector_type(8))) short short8;
typedef __attribute__((ext_vector_type(4))) float f32x4;

namespace {
constexpr int D = 1024;
constexpr int B = 16;
constexpr int T = 2048;
constexpr int L = 16;
constexpr int C = T / L;          // 128 chunks
constexpr float SR  = 0.999f;
constexpr float EPS = 1e-8f;
constexpr int SLICE = L * B * D;  // 262144 floats (1 MB): one out/chunk slice
constexpr int BD = B * D;         // 16384
constexpr int UOFF = 131072;      // float offset of u-stash inside an out slice
constexpr int WOFF = 196608;      // float offset of w-stash inside an out slice
}

__device__ __forceinline__ u16 f2b(float f) {
  unsigned u = __float_as_uint(f);
  unsigned r = (u + 0x7fffu + ((u >> 16) & 1u)) >> 16;
  return (u16)r;
}
__device__ __forceinline__ float b2f(u16 v) {
  return __uint_as_float(((unsigned)v) << 16);
}

__device__ __forceinline__ short8 pack8(float4 a, float4 b) {
  short8 s;
  s[0] = (short)f2b(a.x); s[1] = (short)f2b(a.y);
  s[2] = (short)f2b(a.z); s[3] = (short)f2b(a.w);
  s[4] = (short)f2b(b.x); s[5] = (short)f2b(b.y);
  s[6] = (short)f2b(b.z); s[7] = (short)f2b(b.w);
  return s;
}

// ---------------- spectral norm (f32, small) ----------------

__global__ void mvT_kernel(const float* __restrict__ W, const float* __restrict__ vin,
                           float* __restrict__ vout) {
  int j = blockIdx.x * 256 + threadIdx.x;
  float acc = 0.f;
#pragma unroll 4
  for (int i = 0; i < D; ++i) acc += vin[i] * W[i * D + j];
  vout[j] = acc;
}

__global__ void mvN_kernel(const float* __restrict__ W, const float* __restrict__ vin,
                           float* __restrict__ vout) {
  __shared__ float red[256];
  int i = blockIdx.x, tid = threadIdx.x;
  float acc = 0.f;
  for (int j = tid; j < D; j += 256) acc += W[i * D + j] * vin[j];
  red[tid] = acc; __syncthreads();
  for (int s = 128; s > 0; s >>= 1) {
    if (tid < s) red[tid] += red[tid + s];
    __syncthreads();
  }
  if (tid == 0) vout[i] = red[0];
}

__global__ void scale_kernel(const float* __restrict__ t5, const float* __restrict__ t6,
                             float* __restrict__ scale_out) {
  __shared__ float r5[256], r6[256];
  int tid = threadIdx.x;
  float a5 = 0.f, a6 = 0.f;
  for (int i = tid; i < D; i += 256) { float x5 = t5[i], x6 = t6[i]; a5 += x5 * x5; a6 += x6 * x6; }
  r5[tid] = a5; r6[tid] = a6; __syncthreads();
  for (int s = 128; s > 0; s >>= 1) {
    if (tid < s) { r5[tid] += r5[tid + s]; r6[tid] += r6[tid + s]; }
    __syncthreads();
  }
  if (tid == 0) {
    float n5 = sqrtf(r5[0]), n6 = sqrtf(r6[0]);
    float sigma = n6 / (n5 + EPS);
    scale_out[0] = SR / (sigma + EPS);
  }
}

__global__ void cast_kernel(const float* __restrict__ W, const float* __restrict__ sc,
                            u16* __restrict__ WnB, u16* __restrict__ WnBT) {
  __shared__ float tile[32][33];
  float s = sc[0];
  int tx = threadIdx.x, ty = threadIdx.y;
  int bx = blockIdx.x, by = blockIdx.y;
#pragma unroll
  for (int k = 0; k < 4; ++k) {
    float v = W[(by * 32 + ty + 8 * k) * D + bx * 32 + tx];
    tile[ty + 8 * k][tx] = v;
    WnB[(by * 32 + ty + 8 * k) * D + bx * 32 + tx] = f2b(s * v);
  }
  __syncthreads();
#pragma unroll
  for (int k = 0; k < 4; ++k)
    WnBT[(bx * 32 + ty + 8 * k) * D + by * 32 + tx] = f2b(s * tile[tx][ty + 8 * k]);
}

__global__ __launch_bounds__(256)
void sqb_kernel(const u16* __restrict__ S, const u16* __restrict__ ST,
                u16* __restrict__ O, u16* __restrict__ OT) {
  const int tid = threadIdx.x;
  const int lane = tid & 63, wave = tid >> 6;
  const int lrow = lane & 15, quad = lane >> 4;
  const int m0 = blockIdx.y * 64;
  const int n0 = blockIdx.x * 64 + wave * 16;
  const short8* S8  = (const short8*)S;
  const short8* ST8 = (const short8*)ST;
  f32x4 acc[4];
#pragma unroll
  for (int i = 0; i < 4; ++i) acc[i] = (f32x4){0.f, 0.f, 0.f, 0.f};
  for (int kk = 0; kk < 32; ++kk) {
    short8 bfrag = ST8[(size_t)(n0 + lrow) * 128 + kk * 4 + quad];
#pragma unroll
    for (int mt = 0; mt < 4; ++mt) {
      short8 afrag = S8[(size_t)(m0 + mt * 16 + lrow) * 128 + kk * 4 + quad];
      acc[mt] = __builtin_amdgcn_mfma_f32_16x16x32_bf16(afrag, bfrag, acc[mt], 0, 0, 0);
    }
  }
#pragma unroll
  for (int mt = 0; mt < 4; ++mt)
#pragma unroll
    for (int r = 0; r < 4; ++r) {
      int m = m0 + mt * 16 + quad * 4 + r;
      int n = n0 + lrow;
      u16 v = f2b(acc[mt][r]);
      O[(size_t)m * D + n] = v;
      OT[(size_t)n * D + m] = v;
    }
}

// h row 0 = h0; stash s_0 = h0 at out slice 0; zero 33 barrier slots
__global__ void init_kernel(const float* __restrict__ h0, float* __restrict__ hbuf,
                            float* __restrict__ out, int* cnts, int* gens) {
  int i = blockIdx.x * 256 + threadIdx.x;
  float4 v = ((const float4*)h0)[i];
  ((float4*)hbuf)[i] = v;
  ((float4*)out)[i]  = v;
  if (i < 33) { cnts[i] = 0; gens[i] = 0; }
}

// ---------------- barrier: relaxed poll, single acquire fence ----------------

__device__ __forceinline__ void grid_bar(int* cnt, int* gen, int nblk) {
  __syncthreads();
  if (threadIdx.x == 0) {
    int g = __hip_atomic_load(gen, __ATOMIC_RELAXED, __HIP_MEMORY_SCOPE_AGENT);
    __threadfence();   // release: make this block's step writes visible
    int prev = __hip_atomic_fetch_add(cnt, 1, __ATOMIC_RELAXED, __HIP_MEMORY_SCOPE_AGENT);
    if (prev == nblk - 1) {
      __hip_atomic_store(cnt, 0, __ATOMIC_RELAXED, __HIP_MEMORY_SCOPE_AGENT);
      __hip_atomic_store(gen, g + 1, __ATOMIC_RELEASE, __HIP_MEMORY_SCOPE_AGENT);
    } else {
      while (__hip_atomic_load(gen, __ATOMIC_RELAXED, __HIP_MEMORY_SCOPE_AGENT) == g)
        __builtin_amdgcn_s_sleep(2);
    }
    __builtin_amdgcn_fence(__ATOMIC_ACQUIRE, "agent");  // one inv after wakeup
  }
  __syncthreads();
}

// ---------------- phase 1: grid-wide stepped GEMM ----------------

__global__ __launch_bounds__(512, 2)
void phase1_kernel(const float* __restrict__ x, const u16* __restrict__ WnB,
                   const float* __restrict__ bias, float* __restrict__ hbuf,
                   int* cnts, int* gens) {
  __shared__ u16 Abuf[2][64 * 128];
  const int tid = threadIdx.x;
  const int lane = tid & 63, wave = tid >> 6;
  const int lrow = lane & 15, quad = lane >> 4;
  const int bid = blockIdx.x;
  const int mb = ((bid >> 6) << 3) | (bid & 7);  // group id 0..31 (XCD-local group)
  const int nb = (bid >> 3) & 7;
  const int gr0 = mb * 64;
  const int nw = nb * 128 + wave * 16 + lrow;
  const short8* Wn8 = (const short8*)WnB;

  short8 bfrag[32];
#pragma unroll
  for (int kk = 0; kk < 32; ++kk)
    bfrag[kk] = Wn8[(size_t)nw * 128 + kk * 4 + quad];

  const float bcol = bias[nw];

  const int rr = tid >> 4;
  const int v_ = tid & 15;
  const int row0 = rr, row1 = 32 + rr;
  const int su0 = v_ ^ (row0 & 7), su1 = v_ ^ (row1 & 7);
  const int gra = gr0 + row0, grb = gr0 + row1;
  const int ca = gra >> 4, ba = gra & 15;
  const int cb = grb >> 4, bb = grb & 15;
  const size_t fa_base = (size_t)ba * 1024 + su0 * 8;
  const size_t fb_base = (size_t)bb * 1024 + su1 * 8;
  const int slot0 = row0 * 16 + v_, slot1 = row1 * 16 + v_;

  auto stage_load = [&](int sc, int j, short8& s0, short8& s1) {
    const size_t ta = (size_t)(ca * L + j - 1) * BD + fa_base + sc * 128;
    const size_t tb = (size_t)(cb * L + j - 1) * BD + fb_base + sc * 128;
    float4 x0 = ((const float4*)(x + ta))[0];
    float4 x1 = ((const float4*)(x + ta))[1];
    float4 y0 = ((const float4*)(x + tb))[0];
    float4 y1 = ((const float4*)(x + tb))[1];
    if (j > 1) {
      float4 h0v = ((const float4*)(hbuf + ta))[0];
      float4 h1v = ((const float4*)(hbuf + ta))[1];
      float4 h2v = ((const float4*)(hbuf + tb))[0];
      float4 h3v = ((const float4*)(hbuf + tb))[1];
      x0.x += h0v.x; x0.y += h0v.y; x0.z += h0v.z; x0.w += h0v.w;
      x1.x += h1v.x; x1.y += h1v.y; x1.z += h1v.z; x1.w += h1v.w;
      y0.x += h2v.x; y0.y += h2v.y; y0.z += h2v.z; y0.w += h2v.w;
      y1.x += h3v.x; y1.y += h3v.y; y1.z += h3v.z; y1.w += h3v.w;
    }
    s0 = pack8(x0, x1);
    s1 = pack8(y0, y1);
  };

  for (int j = 1; j <= L; ++j) {
    short8 s0, s1;
    stage_load(0, j, s0, s1);
    ((short8*)Abuf[0])[slot0] = s0;
    ((short8*)Abuf[0])[slot1] = s1;

    f32x4 acc[4];
#pragma unroll
    for (int mt = 0; mt < 4; ++mt) acc[mt] = (f32x4){bcol, bcol, bcol, bcol};

#pragma unroll
    for (int cc = 0; cc < 8; ++cc) {
      const int cur = cc & 1;
      if (cc < 7) stage_load(cc + 1, j, s0, s1);
      __syncthreads();
      const short8* A8 = (const short8*)Abuf[cur];
#pragma unroll
      for (int kp = 0; kp < 4; ++kp) {
#pragma unroll
        for (int mt = 0; mt < 4; ++mt) {
          short8 av = A8[(mt * 16 + lrow) * 16 + ((kp * 4 + quad) ^ (lrow & 7))];
          acc[mt] = __builtin_amdgcn_mfma_f32_16x16x32_bf16(av, bfrag[cc * 4 + kp], acc[mt], 0, 0, 0);
        }
      }
      if (cc < 7) {
        short8* Wd = (short8*)Abuf[cur ^ 1];
        Wd[slot0] = s0;
        Wd[slot1] = s1;
      }
    }

#pragma unroll
    for (int mt = 0; mt < 4; ++mt) {
#pragma unroll
      for (int r = 0; r < 4; ++r) {
        const int gr = gr0 + mt * 16 + quad * 4 + r;
        const int c = gr >> 4, b = gr & 15;
        hbuf[(size_t)(c * L + j) * BD + (size_t)b * 1024 + nw] = acc[mt][r];
      }
    }
    if (j < L) grid_bar(&cnts[mb], &gens[mb], 8);
  }
}

// ---------------- phase 2 helpers ----------------

// Convert f32 state row [16][1024] -> LDS bf16 hi/lo, XOR-swizzled (16B-unit swz by row&7).
template<int NT>
__device__ __forceinline__ void load_state(const float* __restrict__ src,
                                           u16* Ghi, u16* Glo, int tid) {
  const float4* S4 = (const float4*)src;
  ushort4* H4 = (ushort4*)Ghi;
  ushort4* L4 = (ushort4*)Glo;
#pragma unroll
  for (int i = tid; i < 4096; i += NT) {
    float4 v = S4[i];
    ushort4 h, l;
    h.x = f2b(v.x); h.y = f2b(v.y); h.z = f2b(v.z); h.w = f2b(v.w);
    l.x = f2b(v.x - b2f(h.x)); l.y = f2b(v.y - b2f(h.y));
    l.z = f2b(v.z - b2f(h.z)); l.w = f2b(v.w - b2f(h.w));
    int si = i ^ (((i >> 8) & 7) << 1);
    H4[si] = h; L4[si] = l;
  }
}

// acc = M * state (hi/lo split), 4 independent MFMA chains.
__device__ __forceinline__ f32x4 state_matvec(const short8* Ghi8, const short8* Glo8,
                                              const short8* bfrag, int base, int swz) {
  f32x4 a0 = (f32x4){0.f, 0.f, 0.f, 0.f};
  f32x4 a1 = (f32x4){0.f, 0.f, 0.f, 0.f};
  f32x4 a2 = (f32x4){0.f, 0.f, 0.f, 0.f};
  f32x4 a3 = (f32x4){0.f, 0.f, 0.f, 0.f};
#pragma unroll
  for (int kk = 0; kk < 32; kk += 2) {
    int s0 = (base + kk * 4) ^ swz;
    int s1 = (base + kk * 4 + 4) ^ swz;
    a0 = __builtin_amdgcn_mfma_f32_16x16x32_bf16(Ghi8[s0], bfrag[kk],     a0, 0, 0, 0);
    a1 = __builtin_amdgcn_mfma_f32_16x16x32_bf16(Glo8[s0], bfrag[kk],     a1, 0, 0, 0);
    a2 = __builtin_amdgcn_mfma_f32_16x16x32_bf16(Ghi8[s1], bfrag[kk + 1], a2, 0, 0, 0);
    a3 = __builtin_amdgcn_mfma_f32_16x16x32_bf16(Glo8[s1], bfrag[kk + 1], a3, 0, 0, 0);
  }
  return (a0 + a1) + (a2 + a3);
}

// ---------------- phase 2a: parallel u-chains ----------------
// u_{g,j} = A16*u_{g,j-1} + v_{16g+j}, u_{g,1} = v_{16g+1}; groups g=0..7 parallel.
// 64 blocks x 512 thr; block = (k=bid>>3, g=bid&7) -> each group's 8 blocks on one XCD.
// u_{g,j} stashed at out slice (16g+j) + UOFF.
__global__ __launch_bounds__(512, 2)
void p2a_kernel(const u16* __restrict__ A16, const float* __restrict__ hbuf,
                float* __restrict__ out, int* cnts, int* gens) {
  __shared__ u16 Ghi[16 * 1024];
  __shared__ u16 Glo[16 * 1024];
  const int tid = threadIdx.x;
  const int lane = tid & 63, wave = tid >> 6;
  const int lrow = lane & 15, quad = lane >> 4;
  const int g = blockIdx.x & 7, k = blockIdx.x >> 3;
  const int e = k * 128 + wave * 16 + lrow;
  const short8* A8   = (const short8*)A16;
  const short8* Ghi8 = (const short8*)Ghi;
  const short8* Glo8 = (const short8*)Glo;

  short8 bfrag[32];
#pragma unroll
  for (int kk = 0; kk < 32; ++kk)
    bfrag[kk] = A8[(size_t)e * 128 + kk * 4 + quad];

  // u_1 = v_{16g+1}: stash copy (my 128-col slice) + LDS staging
  {
    const float* v1 = hbuf + (size_t)(16 * g + 1) * SLICE;
    float* u1 = out + (size_t)(16 * g + 1) * SLICE + UOFF;
    for (int idx = tid; idx < 2048; idx += 512) {
      int b = idx >> 7, ee = k * 128 + (idx & 127);
      u1[b * 1024 + ee] = v1[b * 1024 + ee];
    }
    load_state<512>(v1, Ghi, Glo, tid);
  }

  const int jmax = (g == 7) ? 15 : 16;   // u_{7,16} (c=128) never needed
  const int base = lrow * 128 + quad;
  const int swz = lrow & 7;
  for (int j = 2; j <= jmax; ++j) {
    const int c = 16 * g + j;
    float vl[4];
#pragma unroll
    for (int r = 0; r < 4; ++r)
      vl[r] = hbuf[(size_t)c * SLICE + (quad * 4 + r) * 1024 + e];
    __syncthreads();
    f32x4 acc = state_matvec(Ghi8, Glo8, bfrag, base, swz);
    float* ust = out + (size_t)c * SLICE + UOFF + e;
#pragma unroll
    for (int r = 0; r < 4; ++r) ust[(quad * 4 + r) * 1024] = acc[r] + vl[r];
    if (j < jmax) {
      grid_bar(&cnts[g], &gens[g], 8);
      load_state<512>(out + (size_t)c * SLICE + UOFF, Ghi, Glo, tid);
    }
  }
}

// ---------------- phase 2b: serial boundary chain, 7 steps of A256 ----------------
// S_{g+1} = A256*S_g + u_{16(g+1)}; S_g written to out slice 16g (s-region).
__global__ __launch_bounds__(256)
void p2b_kernel(const u16* __restrict__ A256, float* __restrict__ out,
                int* cnt, int* gen) {
  __shared__ u16 Ghi[16 * 1024];
  __shared__ u16 Glo[16 * 1024];
  const int tid = threadIdx.x;
  const int lane = tid & 63, wave = tid >> 6;
  const int lrow = lane & 15, quad = lane >> 4;
  const int e = (blockIdx.x * 4 + wave) * 16 + lrow;
  const short8* A8   = (const short8*)A256;
  const short8* Ghi8 = (const short8*)Ghi;
  const short8* Glo8 = (const short8*)Glo;

  short8 bfrag[32];
#pragma unroll
  for (int kk = 0; kk < 32; ++kk)
    bfrag[kk] = A8[(size_t)e * 128 + kk * 4 + quad];

  load_state<256>(out, Ghi, Glo, tid);   // S_0 at slice 0 (h0 stash)

  float hl[4];
#pragma unroll
  for (int r = 0; r < 4; ++r)
    hl[r] = out[(size_t)16 * SLICE + UOFF + (quad * 4 + r) * 1024 + e];

  const int base = lrow * 128 + quad;
  const int swz = lrow & 7;
  for (int g = 0; g < 7; ++g) {
    __syncthreads();
    f32x4 acc = state_matvec(Ghi8, Glo8, bfrag, base, swz);
    float* orow = out + (size_t)(16 * (g + 1)) * SLICE + e;
#pragma unroll
    for (int r = 0; r < 4; ++r) orow[(quad * 4 + r) * 1024] = acc[r] + hl[r];
    if (g < 6) {
#pragma unroll
      for (int r = 0; r < 4; ++r)
        hl[r] = out[(size_t)(16 * (g + 2)) * SLICE + UOFF + (quad * 4 + r) * 1024 + e];
      grid_bar(cnt, gen, gridDim.x);
      load_state<256>(out + (size_t)(16 * (g + 1)) * SLICE, Ghi, Glo, tid);
    }
  }
}

// ---------------- phase 2c: parallel fill ----------------
// w_j = A16*w_{j-1} (w_0 = S_g); s_{16g+j} = w_j + u_{g,j}, j=1..15.
__global__ __launch_bounds__(512, 2)
void p2c_kernel(const u16* __restrict__ A16, float* __restrict__ out,
                int* cnts, int* gens) {
  __shared__ u16 Ghi[16 * 1024];
  __shared__ u16 Glo[16 * 1024];
  const int tid = threadIdx.x;
  const int lane = tid & 63, wave = tid >> 6;
  const int lrow = lane & 15, quad = lane >> 4;
  const int g = blockIdx.x & 7, k = blockIdx.x >> 3;
  const int e = k * 128 + wave * 16 + lrow;
  const short8* A8   = (const short8*)A16;
  const short8* Ghi8 = (const short8*)Ghi;
  const short8* Glo8 = (const short8*)Glo;

  short8 bfrag[32];
#pragma unroll
  for (int kk = 0; kk < 32; ++kk)
    bfrag[kk] = A8[(size_t)e * 128 + kk * 4 + quad];

  load_state<512>(out + (size_t)(16 * g) * SLICE, Ghi, Glo, tid);  // S_g

  const int base = lrow * 128 + quad;
  const int swz = lrow & 7;
  for (int j = 1; j <= 15; ++j) {
    const int c = 16 * g + j;
    float ul[4];
#pragma unroll
    for (int r = 0; r < 4; ++r)
      ul[r] = out[(size_t)c * SLICE + UOFF + (quad * 4 + r) * 1024 + e];
    __syncthreads();
    f32x4 acc = state_matvec(Ghi8, Glo8, bfrag, base, swz);
    float* srow = out + (size_t)c * SLICE + e;
#pragma unroll
    for (int r = 0; r < 4; ++r) srow[(quad * 4 + r) * 1024] = acc[r] + ul[r];
    if (j < 15) {
      float* wrow = out + (size_t)c * SLICE + WOFF + e;
#pragma unroll
      for (int r = 0; r < 4; ++r) wrow[(quad * 4 + r) * 1024] = acc[r];
      grid_bar(&cnts[g], &gens[g], 8);
      load_state<512>(out + (size_t)c * SLICE + WOFF, Ghi, Glo, tid);
    }
  }
}

// Wping[gr][d] = bf16(s_c[b][d]) for gr=(c,b); s_c stashed at out slice c start.
__global__ void w0_kernel(const float* __restrict__ out, u16* __restrict__ Wping) {
  int i4 = blockIdx.x * 256 + threadIdx.x;
  int gr = i4 >> 8, du = i4 & 255;
  int c = gr >> 4, b = gr & 15;
  float4 v = ((const float4*)out)[(size_t)c * (SLICE / 4) + b * 256 + du];
  ushort4 g; g.x = f2b(v.x); g.y = f2b(v.y); g.z = f2b(v.z); g.w = f2b(v.w);
  ((ushort4*)Wping)[i4] = g;
}

// ---------------- phase 3: grid-wide stepped GEMM ----------------

__global__ __launch_bounds__(512, 2)
void phase3_kernel(const u16* __restrict__ WnB, float* __restrict__ hbuf,
                   float* __restrict__ out, u16* __restrict__ Wping,
                   u16* __restrict__ Wpong, int* cnts, int* gens) {
  __shared__ u16 Abuf[2][64 * 128];
  const int tid = threadIdx.x;
  const int lane = tid & 63, wave = tid >> 6;
  const int lrow = lane & 15, quad = lane >> 4;
  const int bid = blockIdx.x;
  const int mb = ((bid >> 6) << 3) | (bid & 7);
  const int nb = (bid >> 3) & 7;
  const int gr0 = mb * 64;
  const int nw = nb * 128 + wave * 16 + lrow;
  const short8* Wn8 = (const short8*)WnB;

  short8 bfrag[32];
#pragma unroll
  for (int kk = 0; kk < 32; ++kk)
    bfrag[kk] = Wn8[(size_t)nw * 128 + kk * 4 + quad];

  const int rr = tid >> 4;
  const int v_ = tid & 15;
  const int row0 = rr, row1 = 32 + rr;
  const int su0 = v_ ^ (row0 & 7), su1 = v_ ^ (row1 & 7);
  const size_t gra = gr0 + row0, grb = gr0 + row1;
  const int slot0 = row0 * 16 + v_, slot1 = row1 * 16 + v_;

  for (int j = 1; j <= L; ++j) {
    const short8* Wsrc = (const short8*)((j & 1) ? Wping : Wpong);
    u16* Wdst = (j & 1) ? Wpong : Wping;

    short8 s0 = Wsrc[gra * 128 + 0 * 16 + su0];
    short8 s1 = Wsrc[grb * 128 + 0 * 16 + su1];
    ((short8*)Abuf[0])[slot0] = s0;
    ((short8*)Abuf[0])[slot1] = s1;

    f32x4 acc[4];
#pragma unroll
    for (int mt = 0; mt < 4; ++mt) acc[mt] = (f32x4){0.f, 0.f, 0.f, 0.f};

#pragma unroll
    for (int cc = 0; cc < 8; ++cc) {
      const int cur = cc & 1;
      if (cc < 7) {
        s0 = Wsrc[gra * 128 + (cc + 1) * 16 + su0];
        s1 = Wsrc[grb * 128 + (cc + 1) * 16 + su1];
      }
      __syncthreads();
      const short8* A8 = (const short8*)Abuf[cur];
#pragma unroll
      for (int kp = 0; kp < 4; ++kp) {
#pragma unroll
        for (int mt = 0; mt < 4; ++mt) {
          short8 av = A8[(mt * 16 + lrow) * 16 + ((kp * 4 + quad) ^ (lrow & 7))];
          acc[mt] = __builtin_amdgcn_mfma_f32_16x16x32_bf16(av, bfrag[cc * 4 + kp], acc[mt], 0, 0, 0);
        }
      }
      if (cc < 7) {
        short8* Wd = (short8*)Abuf[cur ^ 1];
        Wd[slot0] = s0;
        Wd[slot1] = s1;
      }
    }

#pragma unroll
    for (int mt = 0; mt < 4; ++mt) {
#pragma unroll
      for (int r = 0; r < 4; ++r) {
        const int gr = gr0 + mt * 16 + quad * 4 + r;
        const int c = gr >> 4, b = gr & 15;
        float wv = acc[mt][r];
        size_t off = (size_t)(c * L + j) * BD + (size_t)b * 1024 + nw;
        float hv = hbuf[off] + wv;
        hbuf[off] = hv;
        float o = hv * hv / (1.f + __expf(-hv));
        out[off - BD] = o;
        if (j < L) Wdst[(size_t)gr * 1024 + nw] = f2b(wv);
      }
    }
    if (j < L) grid_bar(&cnts[mb], &gens[mb], 8);
  }
}

// ---------------- launch ----------------

extern "C" void kernel_launch(void* const* d_in, const int* in_sizes, int n_in,
                              void* d_out, int out_size, void* d_ws, size_t ws_size,
                              hipStream_t stream) {
  const float* x    = (const float*)d_in[0];
  const float* h0   = (const float*)d_in[1];
  const float* W    = (const float*)d_in[2];
  const float* bias = (const float*)d_in[3];
  const float* u    = (const float*)d_in[4];
  float* out  = (float*)d_out;
  float* hbuf = out + (size_t)T * B * D;

  char* wsb = (char*)d_ws;
  float* va = (float*)wsb;
  float* vb = (float*)(wsb + 4096);
  float* sc = (float*)(wsb + 8192);
  int* cnts = (int*)(wsb + 8192 + 64);   // 33 barrier slots
  int* gens = cnts + 33;
  u16* WnB  = (u16*)(wsb + 16384);
  u16* WnBT = WnB  + (size_t)D * D;
  u16* P1   = WnBT + (size_t)D * D;      // scratch pair / w-ping after squarings
  u16* P1T  = P1   + (size_t)D * D;
  u16* P2   = P1T  + (size_t)D * D;      // A16 (kept) / w-pong region is P2..P2T
  u16* P2T  = P2   + (size_t)D * D;
  u16* Q    = P2T  + (size_t)D * D;      // A64 / A256 ping-pong
  u16* QT   = Q    + (size_t)D * D;

  // spectral norm: 6 matvecs; sigma = ||W v3|| / ||v3||
  mvT_kernel<<<4, 256, 0, stream>>>(W, u, va);
  mvN_kernel<<<1024, 256, 0, stream>>>(W, va, vb);
  mvT_kernel<<<4, 256, 0, stream>>>(W, vb, va);
  mvN_kernel<<<1024, 256, 0, stream>>>(W, va, vb);
  mvT_kernel<<<4, 256, 0, stream>>>(W, vb, va);
  mvN_kernel<<<1024, 256, 0, stream>>>(W, va, vb);
  scale_kernel<<<1, 256, 0, stream>>>(va, vb, sc);

  cast_kernel<<<dim3(32, 32), dim3(32, 8), 0, stream>>>(W, sc, WnB, WnBT);

  // A^16 via 4 bf16 MFMA squarings, then A^256 via 4 more
  sqb_kernel<<<dim3(16, 16), 256, 0, stream>>>(WnB, WnBT, P1, P1T);  // A^2
  sqb_kernel<<<dim3(16, 16), 256, 0, stream>>>(P1, P1T, P2, P2T);    // A^4
  sqb_kernel<<<dim3(16, 16), 256, 0, stream>>>(P2, P2T, P1, P1T);    // A^8
  sqb_kernel<<<dim3(16, 16), 256, 0, stream>>>(P1, P1T, P2, P2T);    // A^16 (kept in P2)
  sqb_kernel<<<dim3(16, 16), 256, 0, stream>>>(P2, P2T, P1, P1T);    // A^32
  sqb_kernel<<<dim3(16, 16), 256, 0, stream>>>(P1, P1T, Q, QT);      // A^64
  sqb_kernel<<<dim3(16, 16), 256, 0, stream>>>(Q, QT, P1, P1T);      // A^128
  sqb_kernel<<<dim3(16, 16), 256, 0, stream>>>(P1, P1T, Q, QT);      // A^256 (Q row-major)

  init_kernel<<<16, 256, 0, stream>>>(h0, hbuf, out, cnts, gens);

  phase1_kernel<<<256, 512, 0, stream>>>(x, WnB, bias, hbuf, cnts, gens);

  p2a_kernel<<<64, 512, 0, stream>>>(P2, hbuf, out, cnts, gens);
  p2b_kernel<<<16, 256, 0, stream>>>(Q, out, &cnts[32], &gens[32]);
  p2c_kernel<<<64, 512, 0, stream>>>(P2, out, cnts, gens);

  w0_kernel<<<2048, 256, 0, stream>>>(out, P1);

  phase3_kernel<<<256, 512, 0, stream>>>(WnB, hbuf, out, P1, P2, cnts, gens);
}